// Round 7
// baseline (313.138 us; speedup 1.0000x reference)
//
#include <hip/hip_runtime.h>

#define N_PTS 1000000
#define EPS 1e-5f
#define SLOPE 0.2f

typedef __attribute__((ext_vector_type(8))) short bf16x8;
typedef __attribute__((ext_vector_type(4))) float f32x4;

__device__ __forceinline__ float leaky(float x) { return fmaxf(x, SLOPE * x); }
__device__ __forceinline__ float bf2f(unsigned int u) {
    union { unsigned int i; float f; } v; v.i = u << 16; return v.f;
}
__device__ __forceinline__ unsigned int f2bf(float f) {
    union { float f; unsigned int i; } v; v.f = f;
    return (v.i + 0x7fffu + ((v.i >> 16) & 1u)) >> 16;
}
__device__ __forceinline__ unsigned int pk(float a, float b) {
    return f2bf(a) | (f2bf(b) << 16);
}
__device__ __forceinline__ short sbf(float f) { return (short)f2bf(f); }
__device__ __forceinline__ bf16x8 asfrag(uint4 r) {
    union { uint4 u; bf16x8 f; } v; v.u = r; return v.f;
}

// ---------------------------------------------------------------------------
// data fp32 [N,4] -> bf16 rows (uint2/row)
// ---------------------------------------------------------------------------
__global__ __launch_bounds__(256) void k_cvt(const float* __restrict__ in,
                                             uint4* __restrict__ out) {
    int t = blockIdx.x * 256 + threadIdx.x;
    if (t >= N_PTS * 4 / 8) return;
    const float4* in4 = (const float4*)in;
    float4 a = in4[t * 2], b = in4[t * 2 + 1];
    uint4 o;
    o.x = pk(a.x, a.y); o.y = pk(a.z, a.w);
    o.z = pk(b.x, b.y); o.w = pk(b.z, b.w);
    out[t] = o;
}

// ---------------------------------------------------------------------------
// conv1 via MFMA. A[p][k=j*4+c] = data_bf[ind[p][j]][c], K=36 -> 2 k-steps.
// All idx + rows staged up front, pinned with sched_barrier so all 12 row
// loads are outstanding simultaneously. Output y1 bf16 [N][16]; BN1 stats.
// ---------------------------------------------------------------------------
__global__ __launch_bounds__(256) void k_conv1(const uint2* __restrict__ dbf,
                                               const int* __restrict__ ind,
                                               const float* __restrict__ w1,
                                               const float* __restrict__ b1,
                                               uint4* __restrict__ y1,
                                               float* __restrict__ stats) {
    __shared__ float tr[4][64][17];
    __shared__ float red[4][32];
    const int tid = threadIdx.x, lane = tid & 63, wid = tid >> 6;
    const int l15 = lane & 15, lq = lane >> 4;
    const int p0 = blockIdx.x * 256 + wid * 64;

    // B fragments: B[k][o] = w1[c][j][o], k = j*4+c
    bf16x8 B0, B1;
#pragma unroll
    for (int e = 0; e < 8; e++) {
        int k = lq * 8 + e;
        B0[e] = sbf(w1[((k & 3) * 9 + (k >> 2)) * 16 + l15]);
        int k1 = 32 + k;
        B1[e] = (k1 < 36) ? sbf(w1[((k1 & 3) * 9 + (k1 >> 2)) * 16 + l15])
                          : (short)0;
    }
    float bias = b1[l15];
    f32x4 acc[4];
#pragma unroll
    for (int t = 0; t < 4; t++) {
#pragma unroll
        for (int r = 0; r < 4; r++) acc[t][r] = bias;
    }

    // stage all indices
    int id0[4], id1[4], id8[4];
#pragma unroll
    for (int t = 0; t < 4; t++) {
        int p = p0 + t * 16 + l15;
        int pc = p < N_PTS ? p : N_PTS - 1;
        const int* ib = ind + (size_t)pc * 9;
        id0[t] = ib[lq * 2];
        id1[t] = ib[lq * 2 + 1];
        id8[t] = ib[8];
    }
    // stage all rows — pin issue order so all 12 loads are in flight
    uint2 ra[4], rb[4], rc[4];
#pragma unroll
    for (int t = 0; t < 4; t++) {
        ra[t] = dbf[id0[t]];
        rb[t] = dbf[id1[t]];
        rc[t] = dbf[id8[t]];
    }
    __builtin_amdgcn_sched_barrier(0);

#pragma unroll
    for (int t = 0; t < 4; t++) {
        bf16x8 A;
        A[0] = (short)ra[t].x; A[1] = (short)(ra[t].x >> 16);
        A[2] = (short)ra[t].y; A[3] = (short)(ra[t].y >> 16);
        A[4] = (short)rb[t].x; A[5] = (short)(rb[t].x >> 16);
        A[6] = (short)rb[t].y; A[7] = (short)(rb[t].y >> 16);
        acc[t] = __builtin_amdgcn_mfma_f32_16x16x32_bf16(A, B0, acc[t], 0, 0, 0);
        bf16x8 A1;
#pragma unroll
        for (int e = 0; e < 8; e++) A1[e] = 0;
        if (lq == 0) {
            A1[0] = (short)rc[t].x; A1[1] = (short)(rc[t].x >> 16);
            A1[2] = (short)rc[t].y; A1[3] = (short)(rc[t].y >> 16);
        }
        acc[t] = __builtin_amdgcn_mfma_f32_16x16x32_bf16(A1, B1, acc[t], 0, 0, 0);
    }

    // epilogue: stats + LDS transpose + bf16 row write
    float s = 0.f, ss = 0.f;
#pragma unroll
    for (int t = 0; t < 4; t++) {
#pragma unroll
        for (int r = 0; r < 4; r++) {
            int p = p0 + t * 16 + lq * 4 + r;
            float v = acc[t][r];
            tr[wid][t * 16 + lq * 4 + r][l15] = v;
            if (p < N_PTS) { s += v; ss += v * v; }
        }
    }
    s += __shfl_xor(s, 16);  s += __shfl_xor(s, 32);
    ss += __shfl_xor(ss, 16); ss += __shfl_xor(ss, 32);
    if (lane < 16) { red[wid][lane] = s; red[wid][16 + lane] = ss; }

    int prow = p0 + lane;
    if (prow < N_PTS) {
        float rv[16];
#pragma unroll
        for (int c = 0; c < 16; c++) rv[c] = tr[wid][lane][c];
        uint4 oa, ob;
        oa.x = pk(rv[0], rv[1]);   oa.y = pk(rv[2], rv[3]);
        oa.z = pk(rv[4], rv[5]);   oa.w = pk(rv[6], rv[7]);
        ob.x = pk(rv[8], rv[9]);   ob.y = pk(rv[10], rv[11]);
        ob.z = pk(rv[12], rv[13]); ob.w = pk(rv[14], rv[15]);
        y1[(size_t)prow * 2] = oa;
        y1[(size_t)prow * 2 + 1] = ob;
    }
    __syncthreads();
    if (tid < 32) {
        float v = red[0][tid] + red[1][tid] + red[2][tid] + red[3][tid];
        atomicAdd(&stats[tid], v);
    }
}

// ---------------------------------------------------------------------------
// k_act: in-place BN1 affine + leaky on y1 bf16 (finalize inlined per block).
// One uint4 = half a row (8 channels, half h = i&1).
// ---------------------------------------------------------------------------
__global__ __launch_bounds__(256) void k_act(uint4* __restrict__ y1,
                                             const float* __restrict__ stats,
                                             const float* __restrict__ g,
                                             const float* __restrict__ be) {
    __shared__ float as_[16], bs_[16];
    if (threadIdx.x < 16) {
        int c = threadIdx.x;
        const float invN = 1.0f / (float)N_PTS;
        float mean = stats[c] * invN;
        float var = stats[16 + c] * invN - mean * mean;
        float a = g[c] * rsqrtf(var + EPS);
        as_[c] = a;
        bs_[c] = be[c] - mean * a;
    }
    __syncthreads();

    const size_t total = (size_t)N_PTS * 2;
    size_t i = (size_t)blockIdx.x * 256 + threadIdx.x;
    size_t stride = (size_t)gridDim.x * 256;
    for (; i < total; i += stride) {
        int h = (int)(i & 1);
        uint4 u = y1[i];
        uint vv[4] = {u.x, u.y, u.z, u.w};
        uint4 o;
        uint ov[4];
#pragma unroll
        for (int q = 0; q < 4; q++) {
            int c = h * 8 + 2 * q;
            float lo = leaky(fmaf(as_[c], bf2f(vv[q] & 0xffffu), bs_[c]));
            float hi = leaky(fmaf(as_[c + 1], bf2f(vv[q] >> 16), bs_[c + 1]));
            ov[q] = pk(lo, hi);
        }
        o.x = ov[0]; o.y = ov[1]; o.z = ov[2]; o.w = ov[3];
        y1[i] = o;
    }
}

// ---------------------------------------------------------------------------
// conv2 via MFMA. A[p][k=j*16+c] = y1a[ind[p][j]][c] (pre-activated).
// K=144 -> 5 k-steps. All 20 gathered 16B half-rows loaded up front and
// PINNED with sched_barrier(0) so all 20 stay outstanding (MLP). Gathered
// rows feed MFMA directly. Fused BN2 stats. y2 fp32 -> d_out.
// ---------------------------------------------------------------------------
__global__ __launch_bounds__(256) void k_conv2(const uint4* __restrict__ u,
                                               const int* __restrict__ ind,
                                               const float* __restrict__ w2,
                                               float* __restrict__ stats,
                                               float4* __restrict__ y2) {
    __shared__ float tr[4][64][17];
    __shared__ float red[4][32];
    const int tid = threadIdx.x, lane = tid & 63, wid = tid >> 6;
    const int l15 = lane & 15, lq = lane >> 4;
    const int jb = lq >> 1, h = lq & 1;
    const int p0 = blockIdx.x * 256 + wid * 64;

    // B fragments: B[k][o] = w2[c][j][o], k = j*16+c (zero-pad k>=144)
    bf16x8 B[5];
#pragma unroll
    for (int s = 0; s < 5; s++) {
#pragma unroll
        for (int e = 0; e < 8; e++) {
            int k = s * 32 + lq * 8 + e;
            short v = 0;
            if (k < 144) v = sbf(w2[((size_t)(k & 15) * 9 + (k >> 4)) * 16 + l15]);
            B[s][e] = v;
        }
    }

    f32x4 acc[4];
#pragma unroll
    for (int t = 0; t < 4; t++) {
#pragma unroll
        for (int r = 0; r < 4; r++) acc[t][r] = 0.f;
    }

    // stage all indices
    int idm[4][5];
#pragma unroll
    for (int t = 0; t < 4; t++) {
        int p = p0 + t * 16 + l15;
        int pc = p < N_PTS ? p : N_PTS - 1;
        const int* ib = ind + (size_t)pc * 9;
#pragma unroll
        for (int s = 0; s < 4; s++) idm[t][s] = ib[2 * s + jb];
        idm[t][4] = ib[8];
    }

    // stage ALL 20 gathered half-rows up front; sched_barrier pins the
    // issue so the compiler cannot sink them back to point-of-use.
    uint4 rA[5], rB[5], rC[5], rD[5];
#define LOADT(dst, t)                                                     \
    do {                                                                  \
        dst[0] = u[(size_t)idm[t][0] * 2 + h];                            \
        dst[1] = u[(size_t)idm[t][1] * 2 + h];                            \
        dst[2] = u[(size_t)idm[t][2] * 2 + h];                            \
        dst[3] = u[(size_t)idm[t][3] * 2 + h];                            \
        dst[4] = u[(size_t)idm[t][4] * 2 + h];                            \
    } while (0)

    LOADT(rA, 0);
    LOADT(rB, 1);
    LOADT(rC, 2);
    LOADT(rD, 3);
#undef LOADT
    __builtin_amdgcn_sched_barrier(0);

    bf16x8 zf;
#pragma unroll
    for (int e = 0; e < 8; e++) zf[e] = 0;

#define COMPT(t, src)                                                     \
    do {                                                                  \
        acc[t] = __builtin_amdgcn_mfma_f32_16x16x32_bf16(asfrag(src[0]), B[0], acc[t], 0, 0, 0); \
        acc[t] = __builtin_amdgcn_mfma_f32_16x16x32_bf16(asfrag(src[1]), B[1], acc[t], 0, 0, 0); \
        acc[t] = __builtin_amdgcn_mfma_f32_16x16x32_bf16(asfrag(src[2]), B[2], acc[t], 0, 0, 0); \
        acc[t] = __builtin_amdgcn_mfma_f32_16x16x32_bf16(asfrag(src[3]), B[3], acc[t], 0, 0, 0); \
        bf16x8 A4 = (lq < 2) ? asfrag(src[4]) : zf;                       \
        acc[t] = __builtin_amdgcn_mfma_f32_16x16x32_bf16(A4, B[4], acc[t], 0, 0, 0); \
    } while (0)

    COMPT(0, rA);
    COMPT(1, rB);
    COMPT(2, rC);
    COMPT(3, rD);
#undef COMPT

    // epilogue: stats + LDS transpose + fp32 row write into d_out
    float s = 0.f, ss = 0.f;
#pragma unroll
    for (int t = 0; t < 4; t++) {
#pragma unroll
        for (int r = 0; r < 4; r++) {
            int p = p0 + t * 16 + lq * 4 + r;
            float v = acc[t][r];
            tr[wid][t * 16 + lq * 4 + r][l15] = v;
            if (p < N_PTS) { s += v; ss += v * v; }
        }
    }
    s += __shfl_xor(s, 16);  s += __shfl_xor(s, 32);
    ss += __shfl_xor(ss, 16); ss += __shfl_xor(ss, 32);
    if (lane < 16) { red[wid][lane] = s; red[wid][16 + lane] = ss; }

    int prow = p0 + lane;
    if (prow < N_PTS) {
        float rv[16];
#pragma unroll
        for (int c = 0; c < 16; c++) rv[c] = tr[wid][lane][c];
        float4* row = y2 + (size_t)prow * 4;
        row[0] = make_float4(rv[0], rv[1], rv[2], rv[3]);
        row[1] = make_float4(rv[4], rv[5], rv[6], rv[7]);
        row[2] = make_float4(rv[8], rv[9], rv[10], rv[11]);
        row[3] = make_float4(rv[12], rv[13], rv[14], rv[15]);
    }
    __syncthreads();
    if (tid < 32) {
        float v = red[0][tid] + red[1][tid] + red[2][tid] + red[3][tid];
        atomicAdd(&stats[tid], v);
    }
}

// ---------------------------------------------------------------------------
// final: out[n][o] = leaky(a2[o]*y2[n][o] + b2[o] + sum_c data[n][c]*wd[o][c])
// in-place on d_out; BN2 finalize inlined per block.
// ---------------------------------------------------------------------------
__global__ __launch_bounds__(256) void k_final(float4* __restrict__ y2,
                                               const float* __restrict__ data,
                                               const float* __restrict__ wd,
                                               const float* __restrict__ stats,
                                               const float* __restrict__ g,
                                               const float* __restrict__ be) {
    __shared__ float wds[64], a2s[16], b2s[16];
    if (threadIdx.x < 64) wds[threadIdx.x] = wd[threadIdx.x];
    if (threadIdx.x < 16) {
        int c = threadIdx.x;
        const float invN = 1.0f / (float)N_PTS;
        float mean = stats[c] * invN;
        float var = stats[16 + c] * invN - mean * mean;
        float a = g[c] * rsqrtf(var + EPS);
        a2s[c] = a;
        b2s[c] = be[c] - mean * a;
    }
    __syncthreads();

    int n = blockIdx.x * 256 + threadIdx.x;
    if (n >= N_PTS) return;

    float4 d = ((const float4*)data)[n];
    float dv[4] = {d.x, d.y, d.z, d.w};
    float4* row = y2 + (size_t)n * 4;
#pragma unroll
    for (int k = 0; k < 4; k++) {
        float4 t = row[k];
        float e[4] = {t.x, t.y, t.z, t.w};
        float r[4];
#pragma unroll
        for (int eo = 0; eo < 4; eo++) {
            int o = k * 4 + eo;
            float res = dv[0] * wds[o * 4 + 0];
            res = fmaf(dv[1], wds[o * 4 + 1], res);
            res = fmaf(dv[2], wds[o * 4 + 2], res);
            res = fmaf(dv[3], wds[o * 4 + 3], res);
            r[eo] = leaky(fmaf(a2s[o], e[eo], b2s[o]) + res);
        }
        row[k] = make_float4(r[0], r[1], r[2], r[3]);
    }
}

extern "C" void kernel_launch(void* const* d_in, const int* in_sizes, int n_in,
                              void* d_out, int out_size, void* d_ws, size_t ws_size,
                              hipStream_t stream) {
    const float* data = (const float*)d_in[0];
    const int* ind    = (const int*)d_in[1];
    const float* w1   = (const float*)d_in[2];
    const float* b1   = (const float*)d_in[3];
    const float* g1   = (const float*)d_in[4];
    const float* be1  = (const float*)d_in[5];
    const float* w2   = (const float*)d_in[6];
    const float* g2   = (const float*)d_in[7];
    const float* be2  = (const float*)d_in[8];
    const float* wd   = (const float*)d_in[9];

    unsigned char* ws = (unsigned char*)d_ws;
    // [0 .. 8e6): data_bf16 rows
    // [8e6 .. 40e6): y1 bf16 rows [N][16] (activated in place by k_act)
    // [40e6 .. +256): stats: [0..31] s1, [32..63] s2
    uint4* dbf4  = (uint4*)ws;
    uint2* dbf2  = (uint2*)ws;
    uint4* y1bf  = (uint4*)(ws + 8000000u);
    float* stats = (float*)(ws + 40000000u);

    hipMemsetAsync(stats, 0, 64 * sizeof(float), stream);

    int cvt_blocks = (N_PTS * 4 / 8 + 255) / 256;   // 1954
    int blk        = (N_PTS + 255) / 256;           // 3907

    k_cvt<<<cvt_blocks, 256, 0, stream>>>(data, dbf4);
    k_conv1<<<blk, 256, 0, stream>>>(dbf2, ind, w1, b1, y1bf, stats);
    k_act<<<2048, 256, 0, stream>>>(y1bf, stats, g1, be1);
    k_conv2<<<blk, 256, 0, stream>>>(y1bf, ind, w2, stats + 32, (float4*)d_out);
    k_final<<<blk, 256, 0, stream>>>((float4*)d_out, data, wd, stats + 32, g2, be2);
}

// Round 8
// 300.046 us; speedup vs baseline: 1.0436x; 1.0436x over previous
//
#include <hip/hip_runtime.h>

#define N_PTS 1000000
#define EPS 1e-5f
#define SLOPE 0.2f

typedef __attribute__((ext_vector_type(8))) short bf16x8;
typedef __attribute__((ext_vector_type(4))) float f32x4;

__device__ __forceinline__ float leaky(float x) { return fmaxf(x, SLOPE * x); }
__device__ __forceinline__ float bf2f(unsigned int u) {
    union { unsigned int i; float f; } v; v.i = u << 16; return v.f;
}
__device__ __forceinline__ unsigned int f2bf(float f) {
    union { float f; unsigned int i; } v; v.f = f;
    return (v.i + 0x7fffu + ((v.i >> 16) & 1u)) >> 16;
}
__device__ __forceinline__ unsigned int pk(float a, float b) {
    return f2bf(a) | (f2bf(b) << 16);
}
__device__ __forceinline__ short sbf(float f) { return (short)f2bf(f); }
__device__ __forceinline__ bf16x8 asfrag(uint4 r) {
    union { uint4 u; bf16x8 f; } v; v.u = r; return v.f;
}

// ---------------------------------------------------------------------------
// data fp32 [N,4] -> bf16 rows (uint2/row)
// ---------------------------------------------------------------------------
__global__ __launch_bounds__(256) void k_cvt(const float* __restrict__ in,
                                             uint4* __restrict__ out) {
    int t = blockIdx.x * 256 + threadIdx.x;
    if (t >= N_PTS * 4 / 8) return;
    const float4* in4 = (const float4*)in;
    float4 a = in4[t * 2], b = in4[t * 2 + 1];
    uint4 o;
    o.x = pk(a.x, a.y); o.y = pk(a.z, a.w);
    o.z = pk(b.x, b.y); o.w = pk(b.z, b.w);
    out[t] = o;
}

// ---------------------------------------------------------------------------
// BN1 finalize: ab[c] = a, ab[16+c] = b  (from sums in stats[0..31])
// ---------------------------------------------------------------------------
__global__ void k_fin1(const float* __restrict__ sums,
                       const float* __restrict__ g,
                       const float* __restrict__ be,
                       float* __restrict__ ab) {
    int c = threadIdx.x;
    if (c < 16) {
        const float invN = 1.0f / (float)N_PTS;
        float mean = sums[c] * invN;
        float var = sums[16 + c] * invN - mean * mean;
        float a = g[c] * rsqrtf(var + EPS);
        ab[c] = a;
        ab[16 + c] = be[c] - mean * a;
    }
}

// ---------------------------------------------------------------------------
// conv1 via MFMA. A[p][k=j*4+c] = data_bf[ind[p][j]][c], K=36 -> 2 k-steps.
// All idx + rows staged up front. Output y1 bf16 [N][16] (RAW pre-BN);
// fused BN1 stats.
// ---------------------------------------------------------------------------
__global__ __launch_bounds__(256) void k_conv1(const uint2* __restrict__ dbf,
                                               const int* __restrict__ ind,
                                               const float* __restrict__ w1,
                                               const float* __restrict__ b1,
                                               uint4* __restrict__ y1,
                                               float* __restrict__ stats) {
    __shared__ float tr[4][64][17];
    __shared__ float red[4][32];
    const int tid = threadIdx.x, lane = tid & 63, wid = tid >> 6;
    const int l15 = lane & 15, lq = lane >> 4;
    const int p0 = blockIdx.x * 256 + wid * 64;

    // B fragments: B[k][o] = w1[c][j][o], k = j*4+c
    bf16x8 B0, B1;
#pragma unroll
    for (int e = 0; e < 8; e++) {
        int k = lq * 8 + e;
        B0[e] = sbf(w1[((k & 3) * 9 + (k >> 2)) * 16 + l15]);
        int k1 = 32 + k;
        B1[e] = (k1 < 36) ? sbf(w1[((k1 & 3) * 9 + (k1 >> 2)) * 16 + l15])
                          : (short)0;
    }
    float bias = b1[l15];
    f32x4 acc[4];
#pragma unroll
    for (int t = 0; t < 4; t++) {
#pragma unroll
        for (int r = 0; r < 4; r++) acc[t][r] = bias;
    }

    // stage all indices
    int id0[4], id1[4], id8[4];
#pragma unroll
    for (int t = 0; t < 4; t++) {
        int p = p0 + t * 16 + l15;
        int pc = p < N_PTS ? p : N_PTS - 1;
        const int* ib = ind + (size_t)pc * 9;
        id0[t] = ib[lq * 2];
        id1[t] = ib[lq * 2 + 1];
        id8[t] = ib[8];
    }
    // stage all rows
    uint2 ra[4], rb[4], rc[4];
#pragma unroll
    for (int t = 0; t < 4; t++) {
        ra[t] = dbf[id0[t]];
        rb[t] = dbf[id1[t]];
        rc[t] = dbf[id8[t]];
    }

#pragma unroll
    for (int t = 0; t < 4; t++) {
        bf16x8 A;
        A[0] = (short)ra[t].x; A[1] = (short)(ra[t].x >> 16);
        A[2] = (short)ra[t].y; A[3] = (short)(ra[t].y >> 16);
        A[4] = (short)rb[t].x; A[5] = (short)(rb[t].x >> 16);
        A[6] = (short)rb[t].y; A[7] = (short)(rb[t].y >> 16);
        acc[t] = __builtin_amdgcn_mfma_f32_16x16x32_bf16(A, B0, acc[t], 0, 0, 0);
        bf16x8 A1;
#pragma unroll
        for (int e = 0; e < 8; e++) A1[e] = 0;
        if (lq == 0) {
            A1[0] = (short)rc[t].x; A1[1] = (short)(rc[t].x >> 16);
            A1[2] = (short)rc[t].y; A1[3] = (short)(rc[t].y >> 16);
        }
        acc[t] = __builtin_amdgcn_mfma_f32_16x16x32_bf16(A1, B1, acc[t], 0, 0, 0);
    }

    // epilogue: stats + LDS transpose + bf16 row write
    float s = 0.f, ss = 0.f;
#pragma unroll
    for (int t = 0; t < 4; t++) {
#pragma unroll
        for (int r = 0; r < 4; r++) {
            int p = p0 + t * 16 + lq * 4 + r;
            float v = acc[t][r];
            tr[wid][t * 16 + lq * 4 + r][l15] = v;
            if (p < N_PTS) { s += v; ss += v * v; }
        }
    }
    s += __shfl_xor(s, 16);  s += __shfl_xor(s, 32);
    ss += __shfl_xor(ss, 16); ss += __shfl_xor(ss, 32);
    if (lane < 16) { red[wid][lane] = s; red[wid][16 + lane] = ss; }

    int prow = p0 + lane;
    if (prow < N_PTS) {
        float rv[16];
#pragma unroll
        for (int c = 0; c < 16; c++) rv[c] = tr[wid][lane][c];
        uint4 oa, ob;
        oa.x = pk(rv[0], rv[1]);   oa.y = pk(rv[2], rv[3]);
        oa.z = pk(rv[4], rv[5]);   oa.w = pk(rv[6], rv[7]);
        ob.x = pk(rv[8], rv[9]);   ob.y = pk(rv[10], rv[11]);
        ob.z = pk(rv[12], rv[13]); ob.w = pk(rv[14], rv[15]);
        y1[(size_t)prow * 2] = oa;
        y1[(size_t)prow * 2 + 1] = ob;
    }
    __syncthreads();
    if (tid < 32) {
        float v = red[0][tid] + red[1][tid] + red[2][tid] + red[3][tid];
        atomicAdd(&stats[tid], v);
    }
}

// ---------------------------------------------------------------------------
// conv2 via MFMA. A[p][k=j*16+c] = leaky(a1[c]*y1[ind[p][j]][c]+b1[c]).
// K=144 -> 5 k-steps. All 20 gathered 16B half-rows staged up front (r6
// config — no sched_barrier); BN1 affine+leaky fused into the unpack (VALU
// overlaps the fetch stalls; conv2 is fetch-throughput-bound at ~3.5 TB/s).
// Fused BN2 stats. y2 -> bf16 scratch (BF=1) or fp32 d_out (BF=0).
// ---------------------------------------------------------------------------
template <bool BF>
__global__ __launch_bounds__(256) void k_conv2(const uint4* __restrict__ u,
                                               const int* __restrict__ ind,
                                               const float* __restrict__ w2,
                                               const float* __restrict__ ab1,
                                               float* __restrict__ stats,
                                               float4* __restrict__ y2f,
                                               uint4* __restrict__ y2b) {
    __shared__ float tr[4][64][17];
    __shared__ float red[4][32];
    const int tid = threadIdx.x, lane = tid & 63, wid = tid >> 6;
    const int l15 = lane & 15, lq = lane >> 4;
    const int jb = lq >> 1, h = lq & 1;
    const int p0 = blockIdx.x * 256 + wid * 64;

    // B fragments: B[k][o] = w2[c][j][o], k = j*16+c (zero-pad k>=144)
    bf16x8 B[5];
#pragma unroll
    for (int s = 0; s < 5; s++) {
#pragma unroll
        for (int e = 0; e < 8; e++) {
            int k = s * 32 + lq * 8 + e;
            short v = 0;
            if (k < 144) v = sbf(w2[((size_t)(k & 15) * 9 + (k >> 4)) * 16 + l15]);
            B[s][e] = v;
        }
    }
    // BN1 affine params for this lane's channel half
    float a1v[8], b1v[8];
#pragma unroll
    for (int e = 0; e < 8; e++) {
        a1v[e] = ab1[h * 8 + e];
        b1v[e] = ab1[16 + h * 8 + e];
    }

    f32x4 acc[4];
#pragma unroll
    for (int t = 0; t < 4; t++) {
#pragma unroll
        for (int r = 0; r < 4; r++) acc[t][r] = 0.f;
    }

    // stage all indices
    int idm[4][5];
#pragma unroll
    for (int t = 0; t < 4; t++) {
        int p = p0 + t * 16 + l15;
        int pc = p < N_PTS ? p : N_PTS - 1;
        const int* ib = ind + (size_t)pc * 9;
#pragma unroll
        for (int s = 0; s < 4; s++) idm[t][s] = ib[2 * s + jb];
        idm[t][4] = ib[8];
    }

    // stage ALL 20 gathered half-rows up front
    uint4 rA[5], rB[5], rC[5], rD[5];
#define LOADT(dst, t)                                                     \
    do {                                                                  \
        dst[0] = u[(size_t)idm[t][0] * 2 + h];                            \
        dst[1] = u[(size_t)idm[t][1] * 2 + h];                            \
        dst[2] = u[(size_t)idm[t][2] * 2 + h];                            \
        dst[3] = u[(size_t)idm[t][3] * 2 + h];                            \
        dst[4] = u[(size_t)idm[t][4] * 2 + h];                            \
    } while (0)

    LOADT(rA, 0);
    LOADT(rB, 1);
    LOADT(rC, 2);
    LOADT(rD, 3);
#undef LOADT

    bf16x8 zf;
#pragma unroll
    for (int e = 0; e < 8; e++) zf[e] = 0;

    // BN1 affine + leaky on a packed half-row, repacked to bf16
#define ACT(rw, dst)                                                      \
    do {                                                                  \
        uint vv_[4] = {rw.x, rw.y, rw.z, rw.w};                           \
        uint ov_[4];                                                      \
        _Pragma("unroll")                                                 \
        for (int q = 0; q < 4; q++) {                                     \
            float lo = leaky(fmaf(a1v[2 * q], bf2f(vv_[q] & 0xffffu), b1v[2 * q])); \
            float hi = leaky(fmaf(a1v[2 * q + 1], bf2f(vv_[q] >> 16), b1v[2 * q + 1])); \
            ov_[q] = pk(lo, hi);                                          \
        }                                                                 \
        dst.x = ov_[0]; dst.y = ov_[1]; dst.z = ov_[2]; dst.w = ov_[3];   \
    } while (0)

#define COMPT(t, src)                                                     \
    do {                                                                  \
        uint4 a0_, a1_, a2_, a3_, a4_;                                    \
        ACT(src[0], a0_); ACT(src[1], a1_); ACT(src[2], a2_);             \
        ACT(src[3], a3_); ACT(src[4], a4_);                               \
        acc[t] = __builtin_amdgcn_mfma_f32_16x16x32_bf16(asfrag(a0_), B[0], acc[t], 0, 0, 0); \
        acc[t] = __builtin_amdgcn_mfma_f32_16x16x32_bf16(asfrag(a1_), B[1], acc[t], 0, 0, 0); \
        acc[t] = __builtin_amdgcn_mfma_f32_16x16x32_bf16(asfrag(a2_), B[2], acc[t], 0, 0, 0); \
        acc[t] = __builtin_amdgcn_mfma_f32_16x16x32_bf16(asfrag(a3_), B[3], acc[t], 0, 0, 0); \
        bf16x8 A4 = (lq < 2) ? asfrag(a4_) : zf;                          \
        acc[t] = __builtin_amdgcn_mfma_f32_16x16x32_bf16(A4, B[4], acc[t], 0, 0, 0); \
    } while (0)

    COMPT(0, rA);
    COMPT(1, rB);
    COMPT(2, rC);
    COMPT(3, rD);
#undef COMPT
#undef ACT

    // epilogue: stats + LDS transpose + row write
    float s = 0.f, ss = 0.f;
#pragma unroll
    for (int t = 0; t < 4; t++) {
#pragma unroll
        for (int r = 0; r < 4; r++) {
            int p = p0 + t * 16 + lq * 4 + r;
            float v = acc[t][r];
            tr[wid][t * 16 + lq * 4 + r][l15] = v;
            if (p < N_PTS) { s += v; ss += v * v; }
        }
    }
    s += __shfl_xor(s, 16);  s += __shfl_xor(s, 32);
    ss += __shfl_xor(ss, 16); ss += __shfl_xor(ss, 32);
    if (lane < 16) { red[wid][lane] = s; red[wid][16 + lane] = ss; }

    int prow = p0 + lane;
    if (prow < N_PTS) {
        float rv[16];
#pragma unroll
        for (int c = 0; c < 16; c++) rv[c] = tr[wid][lane][c];
        if (BF) {
            uint4 oa, ob;
            oa.x = pk(rv[0], rv[1]);   oa.y = pk(rv[2], rv[3]);
            oa.z = pk(rv[4], rv[5]);   oa.w = pk(rv[6], rv[7]);
            ob.x = pk(rv[8], rv[9]);   ob.y = pk(rv[10], rv[11]);
            ob.z = pk(rv[12], rv[13]); ob.w = pk(rv[14], rv[15]);
            y2b[(size_t)prow * 2] = oa;
            y2b[(size_t)prow * 2 + 1] = ob;
        } else {
            float4* row = y2f + (size_t)prow * 4;
            row[0] = make_float4(rv[0], rv[1], rv[2], rv[3]);
            row[1] = make_float4(rv[4], rv[5], rv[6], rv[7]);
            row[2] = make_float4(rv[8], rv[9], rv[10], rv[11]);
            row[3] = make_float4(rv[12], rv[13], rv[14], rv[15]);
        }
    }
    __syncthreads();
    if (tid < 32) {
        float v = red[0][tid] + red[1][tid] + red[2][tid] + red[3][tid];
        atomicAdd(&stats[tid], v);
    }
}

// ---------------------------------------------------------------------------
// final: out[n][o] = leaky(a2[o]*y2[n][o] + b2[o] + sum_c data[n][c]*wd[o][c])
// BF=1: reads bf16 y2 scratch; BF=0: in-place on fp32 d_out.
// BN2 finalize inlined per block from stats.
// ---------------------------------------------------------------------------
template <bool BF>
__global__ __launch_bounds__(256) void k_final(const uint4* __restrict__ y2b,
                                               float4* __restrict__ y2f,
                                               const float* __restrict__ data,
                                               const float* __restrict__ wd,
                                               const float* __restrict__ stats,
                                               const float* __restrict__ g,
                                               const float* __restrict__ be,
                                               float4* __restrict__ out) {
    __shared__ float wds[64], a2s[16], b2s[16];
    if (threadIdx.x < 64) wds[threadIdx.x] = wd[threadIdx.x];
    if (threadIdx.x < 16) {
        int c = threadIdx.x;
        const float invN = 1.0f / (float)N_PTS;
        float mean = stats[c] * invN;
        float var = stats[16 + c] * invN - mean * mean;
        float a = g[c] * rsqrtf(var + EPS);
        a2s[c] = a;
        b2s[c] = be[c] - mean * a;
    }
    __syncthreads();

    int n = blockIdx.x * 256 + threadIdx.x;
    if (n >= N_PTS) return;

    float4 d = ((const float4*)data)[n];
    float dv[4] = {d.x, d.y, d.z, d.w};
    float e[16];
    if (BF) {
        uint4 qa = y2b[(size_t)n * 2], qb = y2b[(size_t)n * 2 + 1];
        uint va[8] = {qa.x, qa.y, qa.z, qa.w, qb.x, qb.y, qb.z, qb.w};
#pragma unroll
        for (int q = 0; q < 8; q++) {
            e[2 * q] = bf2f(va[q] & 0xffffu);
            e[2 * q + 1] = bf2f(va[q] >> 16);
        }
    } else {
        float4* row = y2f + (size_t)n * 4;
#pragma unroll
        for (int k = 0; k < 4; k++) {
            float4 t = row[k];
            e[k * 4 + 0] = t.x; e[k * 4 + 1] = t.y;
            e[k * 4 + 2] = t.z; e[k * 4 + 3] = t.w;
        }
    }
    float r[16];
#pragma unroll
    for (int o = 0; o < 16; o++) {
        float res = dv[0] * wds[o * 4 + 0];
        res = fmaf(dv[1], wds[o * 4 + 1], res);
        res = fmaf(dv[2], wds[o * 4 + 2], res);
        res = fmaf(dv[3], wds[o * 4 + 3], res);
        r[o] = leaky(fmaf(a2s[o], e[o], b2s[o]) + res);
    }
    float4* row = out + (size_t)n * 4;
    row[0] = make_float4(r[0], r[1], r[2], r[3]);
    row[1] = make_float4(r[4], r[5], r[6], r[7]);
    row[2] = make_float4(r[8], r[9], r[10], r[11]);
    row[3] = make_float4(r[12], r[13], r[14], r[15]);
}

extern "C" void kernel_launch(void* const* d_in, const int* in_sizes, int n_in,
                              void* d_out, int out_size, void* d_ws, size_t ws_size,
                              hipStream_t stream) {
    const float* data = (const float*)d_in[0];
    const int* ind    = (const int*)d_in[1];
    const float* w1   = (const float*)d_in[2];
    const float* b1   = (const float*)d_in[3];
    const float* g1   = (const float*)d_in[4];
    const float* be1  = (const float*)d_in[5];
    const float* w2   = (const float*)d_in[6];
    const float* g2   = (const float*)d_in[7];
    const float* be2  = (const float*)d_in[8];
    const float* wd   = (const float*)d_in[9];

    unsigned char* ws = (unsigned char*)d_ws;
    // [0 .. 8e6): data_bf16 rows
    // [8e6 .. 40e6): y1 bf16 rows [N][16] (RAW, pre-BN)
    // big path: [40e6 .. 72e6): y2 bf16; stats at 72e6
    // small path: stats at 40e6
    // stats layout: [0..31] s1, [32..63] s2, [64..95] ab1
    const bool big = ws_size >= 72000000u + 512u;
    uint4* dbf4  = (uint4*)ws;
    uint2* dbf2  = (uint2*)ws;
    uint4* y1bf  = (uint4*)(ws + 8000000u);
    uint4* y2bf  = big ? (uint4*)(ws + 40000000u) : (uint4*)nullptr;
    float* stats = (float*)(ws + (big ? 72000000u : 40000000u));

    hipMemsetAsync(stats, 0, 64 * sizeof(float), stream);

    int cvt_blocks = (N_PTS * 4 / 8 + 255) / 256;   // 1954
    int blk        = (N_PTS + 255) / 256;           // 3907

    k_cvt<<<cvt_blocks, 256, 0, stream>>>(data, dbf4);
    k_conv1<<<blk, 256, 0, stream>>>(dbf2, ind, w1, b1, y1bf, stats);
    k_fin1<<<1, 64, 0, stream>>>(stats, g1, be1, stats + 64);
    if (big) {
        k_conv2<true><<<blk, 256, 0, stream>>>(y1bf, ind, w2, stats + 64,
                                               stats + 32, nullptr, y2bf);
        k_final<true><<<blk, 256, 0, stream>>>(y2bf, nullptr, data, wd,
                                               stats + 32, g2, be2,
                                               (float4*)d_out);
    } else {
        k_conv2<false><<<blk, 256, 0, stream>>>(y1bf, ind, w2, stats + 64,
                                                stats + 32, (float4*)d_out,
                                                nullptr);
        k_final<false><<<blk, 256, 0, stream>>>(nullptr, (float4*)d_out, data,
                                                wd, stats + 32, g2, be2,
                                                (float4*)d_out);
    }
}